// Round 1
// baseline (1697.908 us; speedup 1.0000x reference)
//
#include <hip/hip_runtime.h>
#include <hip/hip_bf16.h>
#include <math.h>

// Problem constants
#define Bn 16
#define Cc 256
#define Hh 64
#define Ww 64
#define HW 4096
#define C2 512
#define Pp 65536          // Bn*HW
#define EPSc 1e-5f

// ---------------------------------------------------------------------------
// Kernel 0: combine weights.
// W1[o,c]   = sum_m w_poly[o,m] * freq_real[m] * w_expand[m,c]
// W1g[o,c]  = W1[o,c] * gamma[c]
// bias1[o]  = sum_c W1[o,c] * beta[c]
// grid 512 (one block per o), 256 threads (one per c)
// ---------------------------------------------------------------------------
__global__ __launch_bounds__(256)
void combine_weights(const float* __restrict__ w_expand,
                     const float* __restrict__ freq_real,
                     const float* __restrict__ w_poly,
                     const float* __restrict__ gamma,
                     const float* __restrict__ beta,
                     float* __restrict__ W1g,
                     float* __restrict__ bias1) {
    int o = blockIdx.x;
    int c = threadIdx.x;
    float acc = 0.f;
    const float* wp = w_poly + (size_t)o * C2;
    for (int m = 0; m < C2; ++m) {
        acc += wp[m] * freq_real[m] * w_expand[(size_t)m * Cc + c];
    }
    W1g[(size_t)o * Cc + c] = acc * gamma[c];
    __shared__ float red[256];
    red[c] = acc * beta[c];
    __syncthreads();
    for (int s = 128; s > 0; s >>= 1) {
        if (c < s) red[c] += red[c + s];
        __syncthreads();
    }
    if (c == 0) bias1[o] = red[0];
}

// ---------------------------------------------------------------------------
// Kernel 1: LayerNorm stats per spatial position (over C=256 channels).
// grid 256 x 256 threads, one thread per position.
// ---------------------------------------------------------------------------
__global__ __launch_bounds__(256)
void ln_stats(const float* __restrict__ f,
              float* __restrict__ mu,
              float* __restrict__ rstd) {
    int p = blockIdx.x * 256 + threadIdx.x;   // 0..65535
    int b = p >> 12;
    int s = p & 4095;
    const float* base = f + (size_t)b * Cc * HW + s;
    float sum = 0.f, sumsq = 0.f;
#pragma unroll 8
    for (int c = 0; c < Cc; ++c) {
        float v = base[(size_t)c * HW];
        sum += v;
        sumsq += v * v;
    }
    float m = sum * (1.0f / Cc);
    float var = sumsq * (1.0f / Cc) - m * m;
    mu[p] = m;
    rstd[p] = rsqrtf(var + EPSc);
}

// ---------------------------------------------------------------------------
// Kernel 2: GEMM1  f5[b,o,s] = sum_c W1g[o,c] * (f[b,c,s]-mu)*rstd + bias1[o]
// M=512, K=256, N=4096 per batch. Tile 64x64, 256 threads, 4x4 per thread.
// Output stored as bf16.
// grid: (mt=8, nt=64, b=16)  -- mt fastest so consecutive blocks share f tile
// ---------------------------------------------------------------------------
__global__ __launch_bounds__(256)
void gemm1(const float* __restrict__ f,
           const float* __restrict__ W1g,
           const float* __restrict__ bias1,
           const float* __restrict__ mu,
           const float* __restrict__ rstd,
           __hip_bfloat16* __restrict__ f5) {
    __shared__ float As[16][68];   // [k][m] transposed, padded
    __shared__ float Bs[16][68];   // [k][n] padded

    int mt = blockIdx.x, nt = blockIdx.y, b = blockIdx.z;
    int m0 = mt * 64, s0 = nt * 64;
    int tid = threadIdx.x;
    int tn = (tid & 15) * 4;
    int tm = (tid >> 4) * 4;

    float acc[4][4] = {};
    const float* fb = f + (size_t)b * Cc * HW + s0;
    int pbase = b * HW + s0;

    for (int k0 = 0; k0 < Cc; k0 += 16) {
        // stage A (W1g tile, transposed into [k][m])
        for (int i = tid; i < 1024; i += 256) {
            int kk = i & 15, mm = i >> 4;
            As[kk][mm] = W1g[(size_t)(m0 + mm) * Cc + k0 + kk];
        }
        // stage B (normalized input tile [k][n])
        for (int i = tid; i < 1024; i += 256) {
            int kk = i >> 6, nn = i & 63;
            int p = pbase + nn;
            float v = fb[(size_t)(k0 + kk) * HW + nn];
            Bs[kk][nn] = (v - mu[p]) * rstd[p];
        }
        __syncthreads();
#pragma unroll
        for (int k = 0; k < 16; ++k) {
            float4 a = *(const float4*)&As[k][tm];
            float4 bv = *(const float4*)&Bs[k][tn];
            acc[0][0] += a.x * bv.x; acc[0][1] += a.x * bv.y;
            acc[0][2] += a.x * bv.z; acc[0][3] += a.x * bv.w;
            acc[1][0] += a.y * bv.x; acc[1][1] += a.y * bv.y;
            acc[1][2] += a.y * bv.z; acc[1][3] += a.y * bv.w;
            acc[2][0] += a.z * bv.x; acc[2][1] += a.z * bv.y;
            acc[2][2] += a.z * bv.z; acc[2][3] += a.z * bv.w;
            acc[3][0] += a.w * bv.x; acc[3][1] += a.w * bv.y;
            acc[3][2] += a.w * bv.z; acc[3][3] += a.w * bv.w;
        }
        __syncthreads();
    }

#pragma unroll
    for (int i = 0; i < 4; ++i) {
        float bias = bias1[m0 + tm + i];
        __hip_bfloat16 vals[4];
#pragma unroll
        for (int j = 0; j < 4; ++j)
            vals[j] = __float2bfloat16(acc[i][j] + bias);
        *(uint2*)&f5[((size_t)b * C2 + (m0 + tm + i)) * HW + s0 + tn] = *(const uint2*)vals;
    }
}

// ---------------------------------------------------------------------------
// Kernel 3: fused tail. Per block: one (b, h, 32-wide w tile).
//  phase 0: t[k][n]  = dwconv3x3(f5)           -> LDS (512x32 fp32 = 64 KB)
//  phase 1: g        = w_pw (512x512) @ t       -> registers (16m x 4n / thread)
//           f7       = gelu(g)*g                -> back into same LDS
//  phase 2: f8       = w_final (256x512) @ f7   -> registers (8m x 4n / thread)
//  epilogue: out = f + f8
// ---------------------------------------------------------------------------
#define TN3 32
__global__ __launch_bounds__(256)
void fused_tail(const __hip_bfloat16* __restrict__ f5,
                const float* __restrict__ w_dw,
                const float* __restrict__ w_pw,
                const float* __restrict__ w_final,
                const float* __restrict__ f,
                float* __restrict__ out) {
    __shared__ float smem[C2 * TN3];   // 64 KB, reused t -> f7

    int wt = blockIdx.x;       // 0..1
    int h  = blockIdx.y;       // 0..63
    int b  = blockIdx.z;       // 0..15
    int w0 = wt * TN3;
    int tid = threadIdx.x;

    // ---- phase 0: depthwise 3x3 into LDS ----
    const __hip_bfloat16* f5b = f5 + (size_t)b * C2 * HW;
    for (int i = tid; i < C2 * TN3; i += 256) {
        int n = i & (TN3 - 1);
        int k = i >> 5;
        int w = w0 + n;
        const float* wd = w_dw + k * 9;
        const __hip_bfloat16* fk = f5b + (size_t)k * HW;
        float acc = 0.f;
#pragma unroll
        for (int dy = -1; dy <= 1; ++dy) {
            int hh = h + dy;
            if ((unsigned)hh >= Hh) continue;
#pragma unroll
            for (int dx = -1; dx <= 1; ++dx) {
                int ww = w + dx;
                if ((unsigned)ww >= Ww) continue;
                acc += wd[(dy + 1) * 3 + (dx + 1)] * __bfloat162float(fk[hh * Ww + ww]);
            }
        }
        smem[k * TN3 + n] = acc;
    }
    __syncthreads();

    // ---- phase 1: g = w_pw @ t, 256 threads = 32 m-groups x 8 n-groups ----
    int ng = tid & 7;
    int mg = tid >> 3;
    int n0 = ng * 4;
    int m0 = mg * 16;

    float acc[16][4] = {};
    for (int k = 0; k < C2; k += 4) {
        float bb[4][4];
#pragma unroll
        for (int kk = 0; kk < 4; ++kk)
            *(float4*)bb[kk] = *(const float4*)&smem[(k + kk) * TN3 + n0];
#pragma unroll
        for (int i = 0; i < 16; ++i) {
            float4 av = *(const float4*)&w_pw[(size_t)(m0 + i) * C2 + k];
#pragma unroll
            for (int j = 0; j < 4; ++j)
                acc[i][j] += av.x * bb[0][j] + av.y * bb[1][j] +
                             av.z * bb[2][j] + av.w * bb[3][j];
        }
    }
    __syncthreads();   // everyone done reading t

    // ---- gating: f7 = gelu(g)*g, write into same LDS ----
#pragma unroll
    for (int i = 0; i < 16; ++i) {
        float vals[4];
#pragma unroll
        for (int j = 0; j < 4; ++j) {
            float v = acc[i][j];
            float g = 0.5f * v * (1.0f + erff(v * 0.70710678118f));
            vals[j] = g * v;
        }
        *(float4*)&smem[(m0 + i) * TN3 + n0] = *(const float4*)vals;
    }
    __syncthreads();

    // ---- phase 2: f8 = w_final @ f7, 32 m-groups x 8 m each ----
    int m20 = mg * 8;
    float acc2[8][4] = {};
    for (int k = 0; k < C2; k += 4) {
        float bb[4][4];
#pragma unroll
        for (int kk = 0; kk < 4; ++kk)
            *(float4*)bb[kk] = *(const float4*)&smem[(k + kk) * TN3 + n0];
#pragma unroll
        for (int i = 0; i < 8; ++i) {
            float4 av = *(const float4*)&w_final[(size_t)(m20 + i) * C2 + k];
#pragma unroll
            for (int j = 0; j < 4; ++j)
                acc2[i][j] += av.x * bb[0][j] + av.y * bb[1][j] +
                              av.z * bb[2][j] + av.w * bb[3][j];
        }
    }

    // ---- epilogue: out = f + f8 ----
#pragma unroll
    for (int i = 0; i < 8; ++i) {
        int m = m20 + i;
        size_t off = ((size_t)b * Cc + m) * HW + h * Ww + w0 + n0;
        float4 fv = *(const float4*)&f[off];
        float4 ov;
        ov.x = fv.x + acc2[i][0];
        ov.y = fv.y + acc2[i][1];
        ov.z = fv.z + acc2[i][2];
        ov.w = fv.w + acc2[i][3];
        *(float4*)&out[off] = ov;
    }
}

// ---------------------------------------------------------------------------
extern "C" void kernel_launch(void* const* d_in, const int* in_sizes, int n_in,
                              void* d_out, int out_size, void* d_ws, size_t ws_size,
                              hipStream_t stream) {
    const float* f         = (const float*)d_in[0];
    const float* ln_gamma  = (const float*)d_in[1];
    const float* ln_beta   = (const float*)d_in[2];
    const float* w_expand  = (const float*)d_in[3];
    const float* freq_real = (const float*)d_in[4];
    // d_in[5] = freq_imag: provably unused (Re((r+ij)*x) for real x = r*x)
    const float* w_poly    = (const float*)d_in[6];
    const float* w_dw      = (const float*)d_in[7];
    const float* w_pw      = (const float*)d_in[8];
    const float* w_final   = (const float*)d_in[9];
    float* out = (float*)d_out;

    // workspace layout
    char* ws = (char*)d_ws;
    __hip_bfloat16* f5 = (__hip_bfloat16*)ws;                    // 64 MiB
    float* W1g   = (float*)(ws + (size_t)67108864);              // 512 KB
    float* bias1 = W1g + (size_t)C2 * Cc;                        // 2 KB
    float* muA   = bias1 + C2;                                   // 256 KB
    float* rstdA = muA + Pp;                                     // 256 KB

    combine_weights<<<dim3(C2), dim3(256), 0, stream>>>(
        w_expand, freq_real, w_poly, ln_gamma, ln_beta, W1g, bias1);

    ln_stats<<<dim3(Pp / 256), dim3(256), 0, stream>>>(f, muA, rstdA);

    gemm1<<<dim3(8, 64, Bn), dim3(256), 0, stream>>>(
        f, W1g, bias1, muA, rstdA, f5);

    fused_tail<<<dim3(Ww / TN3, Hh, Bn), dim3(256), 0, stream>>>(
        f5, w_dw, w_pw, w_final, f, out);
}

// Round 2
// 698.326 us; speedup vs baseline: 2.4314x; 2.4314x over previous
//
#include <hip/hip_runtime.h>
#include <hip/hip_bf16.h>
#include <math.h>

// Problem constants
#define Bn 16
#define Cc 256
#define Hh 64
#define Ww 64
#define HW 4096
#define C2 512
#define Pp 65536          // Bn*HW
#define EPSc 1e-5f

typedef __attribute__((ext_vector_type(8))) short short8;
typedef __attribute__((ext_vector_type(4))) float floatx4;

// ---------------------------------------------------------------------------
// Kernel 0: combine weights.
// W1[o,c]   = sum_m w_poly[o,m] * freq_real[m] * w_expand[m,c]
// W1g[o,c]  = W1[o,c] * gamma[c]
// bias1[o]  = sum_c W1[o,c] * beta[c]
// ---------------------------------------------------------------------------
__global__ __launch_bounds__(256)
void combine_weights(const float* __restrict__ w_expand,
                     const float* __restrict__ freq_real,
                     const float* __restrict__ w_poly,
                     const float* __restrict__ gamma,
                     const float* __restrict__ beta,
                     float* __restrict__ W1g,
                     float* __restrict__ bias1) {
    int o = blockIdx.x;
    int c = threadIdx.x;
    float acc = 0.f;
    const float* wp = w_poly + (size_t)o * C2;
    for (int m = 0; m < C2; ++m) {
        acc += wp[m] * freq_real[m] * w_expand[(size_t)m * Cc + c];
    }
    W1g[(size_t)o * Cc + c] = acc * gamma[c];
    __shared__ float red[256];
    red[c] = acc * beta[c];
    __syncthreads();
    for (int s = 128; s > 0; s >>= 1) {
        if (c < s) red[c] += red[c + s];
        __syncthreads();
    }
    if (c == 0) bias1[o] = red[0];
}

// ---------------------------------------------------------------------------
// Kernel 0b: fp32 -> bf16 weight conversion (w_pw 512x512, w_final 256x512)
// ---------------------------------------------------------------------------
__global__ __launch_bounds__(256)
void to_bf16(const float* __restrict__ a, __hip_bfloat16* __restrict__ o, int n) {
    int i = (blockIdx.x * 256 + threadIdx.x) * 4;
    if (i < n) {
        float4 v = *(const float4*)&a[i];
        __hip_bfloat16 r[4];
        r[0] = __float2bfloat16(v.x);
        r[1] = __float2bfloat16(v.y);
        r[2] = __float2bfloat16(v.z);
        r[3] = __float2bfloat16(v.w);
        *(uint2*)&o[i] = *(const uint2*)r;
    }
}

// ---------------------------------------------------------------------------
// Kernel 1: LayerNorm stats per spatial position (over C=256 channels).
// ---------------------------------------------------------------------------
__global__ __launch_bounds__(256)
void ln_stats(const float* __restrict__ f,
              float* __restrict__ mu,
              float* __restrict__ rstd) {
    int p = blockIdx.x * 256 + threadIdx.x;   // 0..65535
    int b = p >> 12;
    int s = p & 4095;
    const float* base = f + (size_t)b * Cc * HW + s;
    float sum = 0.f, sumsq = 0.f;
#pragma unroll 8
    for (int c = 0; c < Cc; ++c) {
        float v = base[(size_t)c * HW];
        sum += v;
        sumsq += v * v;
    }
    float m = sum * (1.0f / Cc);
    float var = sumsq * (1.0f / Cc) - m * m;
    mu[p] = m;
    rstd[p] = rsqrtf(var + EPSc);
}

// ---------------------------------------------------------------------------
// Kernel 2: GEMM1  f5[b,o,s] = sum_c W1g[o,c] * (f[b,c,s]-mu)*rstd + bias1[o]
// (fp32 VALU version — to be MFMA-ized next round if it dominates)
// ---------------------------------------------------------------------------
__global__ __launch_bounds__(256)
void gemm1(const float* __restrict__ f,
           const float* __restrict__ W1g,
           const float* __restrict__ bias1,
           const float* __restrict__ mu,
           const float* __restrict__ rstd,
           __hip_bfloat16* __restrict__ f5) {
    __shared__ float As[16][68];   // [k][m] transposed, padded
    __shared__ float Bs[16][68];   // [k][n] padded

    int mt = blockIdx.x, nt = blockIdx.y, b = blockIdx.z;
    int m0 = mt * 64, s0 = nt * 64;
    int tid = threadIdx.x;
    int tn = (tid & 15) * 4;
    int tm = (tid >> 4) * 4;

    float acc[4][4] = {};
    const float* fb = f + (size_t)b * Cc * HW + s0;
    int pbase = b * HW + s0;

    for (int k0 = 0; k0 < Cc; k0 += 16) {
        for (int i = tid; i < 1024; i += 256) {
            int kk = i & 15, mm = i >> 4;
            As[kk][mm] = W1g[(size_t)(m0 + mm) * Cc + k0 + kk];
        }
        for (int i = tid; i < 1024; i += 256) {
            int kk = i >> 6, nn = i & 63;
            int p = pbase + nn;
            float v = fb[(size_t)(k0 + kk) * HW + nn];
            Bs[kk][nn] = (v - mu[p]) * rstd[p];
        }
        __syncthreads();
#pragma unroll
        for (int k = 0; k < 16; ++k) {
            float4 a = *(const float4*)&As[k][tm];
            float4 bv = *(const float4*)&Bs[k][tn];
            acc[0][0] += a.x * bv.x; acc[0][1] += a.x * bv.y;
            acc[0][2] += a.x * bv.z; acc[0][3] += a.x * bv.w;
            acc[1][0] += a.y * bv.x; acc[1][1] += a.y * bv.y;
            acc[1][2] += a.y * bv.z; acc[1][3] += a.y * bv.w;
            acc[2][0] += a.z * bv.x; acc[2][1] += a.z * bv.y;
            acc[2][2] += a.z * bv.z; acc[2][3] += a.z * bv.w;
            acc[3][0] += a.w * bv.x; acc[3][1] += a.w * bv.y;
            acc[3][2] += a.w * bv.z; acc[3][3] += a.w * bv.w;
        }
        __syncthreads();
    }

#pragma unroll
    for (int i = 0; i < 4; ++i) {
        float bias = bias1[m0 + tm + i];
        __hip_bfloat16 vals[4];
#pragma unroll
        for (int j = 0; j < 4; ++j)
            vals[j] = __float2bfloat16(acc[i][j] + bias);
        *(uint2*)&f5[((size_t)b * C2 + (m0 + tm + i)) * HW + s0 + tn] = *(const uint2*)vals;
    }
}

// ---------------------------------------------------------------------------
// Kernel 3: fused tail, MFMA version. Per block: one (b, h, 32-wide w tile).
//  phase 0: tT[n][k] = dwconv3x3(f5) as bf16 -> LDS (32 x 520 pitch = 33.3 KB)
//  phase 1: g = w_pw @ t via mfma_16x16x32_bf16; gelu(g)*g -> back into tT
//  phase 2: f8 = w_final @ f7 via mfma; out = f + f8
// LDS 33.3 KB -> 4 blocks/CU. Pitch 520 bf16: +8 pad = 4-bank shift per row,
// b128 frag reads and b64 f7 writes are exactly bank-balanced (no conflicts).
// ---------------------------------------------------------------------------
#define TN3 32
#define TPITCH 520

__global__ __launch_bounds__(256, 4)
void fused_tail(const __hip_bfloat16* __restrict__ f5,
                const float* __restrict__ w_dw,
                const __hip_bfloat16* __restrict__ w_pw_b,
                const __hip_bfloat16* __restrict__ w_final_b,
                const float* __restrict__ f,
                float* __restrict__ out) {
    __shared__ __hip_bfloat16 tT[TN3 * TPITCH];   // 33,280 B, reused t -> f7

    int wt = blockIdx.x;       // 0..1
    int h  = blockIdx.y;       // 0..63
    int b  = blockIdx.z;       // 0..15
    int w0 = wt * TN3;
    int tid = threadIdx.x;
    int lane = tid & 63;
    int wave = tid >> 6;
    int col = lane & 15;
    int quad = lane >> 4;

    // ---- phase 0: depthwise 3x3 -> tT[n][k] (bf16) ----
    // task t: k = t>>2 (channel), n0 = (t&3)*8 (8 consecutive w outputs)
    const __hip_bfloat16* f5b = f5 + (size_t)b * C2 * HW;
#pragma unroll
    for (int it = 0; it < 8; ++it) {
        int t = it * 256 + tid;
        int k = t >> 2;
        int n0 = (t & 3) * 8;
        int w = w0 + n0;
        const float* wd = w_dw + k * 9;
        float wreg[9];
#pragma unroll
        for (int i = 0; i < 9; ++i) wreg[i] = wd[i];
        float win[3][10];
#pragma unroll
        for (int dy = 0; dy < 3; ++dy) {
            int hh = h + dy - 1;
            if ((unsigned)hh < Hh) {
                const __hip_bfloat16* row = f5b + (size_t)k * HW + hh * Ww;
                uint4 v8 = *(const uint4*)&row[w];
                const __hip_bfloat16* pv = (const __hip_bfloat16*)&v8;
#pragma unroll
                for (int j = 0; j < 8; ++j) win[dy][j + 1] = __bfloat162float(pv[j]);
                win[dy][0] = (w > 0) ? __bfloat162float(row[w - 1]) : 0.f;
                win[dy][9] = (w + 8 < Ww) ? __bfloat162float(row[w + 8]) : 0.f;
            } else {
#pragma unroll
                for (int j = 0; j < 10; ++j) win[dy][j] = 0.f;
            }
        }
#pragma unroll
        for (int j = 0; j < 8; ++j) {
            float acc = 0.f;
#pragma unroll
            for (int dy = 0; dy < 3; ++dy)
#pragma unroll
                for (int dx = 0; dx < 3; ++dx)
                    acc += wreg[dy * 3 + dx] * win[dy][j + dx];
            tT[(n0 + j) * TPITCH + k] = __float2bfloat16(acc);
        }
    }
    __syncthreads();

    // ---- phase 1: g = w_pw @ t. Wave handles 128 m-rows (8 m-tiles x 2 n-tiles)
    floatx4 acc[8][2];
#pragma unroll
    for (int mt = 0; mt < 8; ++mt)
#pragma unroll
        for (int nt = 0; nt < 2; ++nt)
            acc[mt][nt] = (floatx4){0.f, 0.f, 0.f, 0.f};

    int wm0 = wave * 128;
    for (int ks = 0; ks < 16; ++ks) {
        int k0 = ks * 32;
        short8 bfrag[2];
#pragma unroll
        for (int nt = 0; nt < 2; ++nt)
            bfrag[nt] = *(const short8*)&tT[(nt * 16 + col) * TPITCH + k0 + quad * 8];
#pragma unroll
        for (int mt = 0; mt < 8; ++mt) {
            short8 afrag = *(const short8*)&w_pw_b[(size_t)(wm0 + mt * 16 + col) * C2 + k0 + quad * 8];
            acc[mt][0] = __builtin_amdgcn_mfma_f32_16x16x32_bf16(afrag, bfrag[0], acc[mt][0], 0, 0, 0);
            acc[mt][1] = __builtin_amdgcn_mfma_f32_16x16x32_bf16(afrag, bfrag[1], acc[mt][1], 0, 0, 0);
        }
    }
    __syncthreads();   // everyone done reading tT

    // ---- gating: f7 = gelu(g)*g -> back into tT (same [n][k] layout) ----
#pragma unroll
    for (int mt = 0; mt < 8; ++mt)
#pragma unroll
        for (int nt = 0; nt < 2; ++nt) {
            __hip_bfloat16 v4[4];
#pragma unroll
            for (int r = 0; r < 4; ++r) {
                float v = acc[mt][nt][r];
                float g = 0.5f * v * (1.0f + erff(v * 0.70710678118f));
                v4[r] = __float2bfloat16(g * v);
            }
            // k2 rows wm0+mt*16+quad*4 .. +3, col n = nt*16+col
            *(uint2*)&tT[(nt * 16 + col) * TPITCH + wm0 + mt * 16 + quad * 4] = *(const uint2*)v4;
        }
    __syncthreads();

    // ---- phase 2: f8 = w_final @ f7. Wave handles 64 m-rows (4 m-tiles) ----
    floatx4 acc2[4][2];
#pragma unroll
    for (int mt = 0; mt < 4; ++mt)
#pragma unroll
        for (int nt = 0; nt < 2; ++nt)
            acc2[mt][nt] = (floatx4){0.f, 0.f, 0.f, 0.f};

    int wm2 = wave * 64;
    for (int ks = 0; ks < 16; ++ks) {
        int k0 = ks * 32;
        short8 bfrag[2];
#pragma unroll
        for (int nt = 0; nt < 2; ++nt)
            bfrag[nt] = *(const short8*)&tT[(nt * 16 + col) * TPITCH + k0 + quad * 8];
#pragma unroll
        for (int mt = 0; mt < 4; ++mt) {
            short8 afrag = *(const short8*)&w_final_b[(size_t)(wm2 + mt * 16 + col) * C2 + k0 + quad * 8];
            acc2[mt][0] = __builtin_amdgcn_mfma_f32_16x16x32_bf16(afrag, bfrag[0], acc2[mt][0], 0, 0, 0);
            acc2[mt][1] = __builtin_amdgcn_mfma_f32_16x16x32_bf16(afrag, bfrag[1], acc2[mt][1], 0, 0, 0);
        }
    }

    // ---- epilogue: out = f + f8 ----
    const float* fb = f + (size_t)b * Cc * HW + h * Ww + w0;
    float* ob = out + (size_t)b * Cc * HW + h * Ww + w0;
#pragma unroll
    for (int mt = 0; mt < 4; ++mt)
#pragma unroll
        for (int nt = 0; nt < 2; ++nt)
#pragma unroll
            for (int r = 0; r < 4; ++r) {
                int m = wm2 + mt * 16 + quad * 4 + r;
                int n = nt * 16 + col;
                size_t off = (size_t)m * HW + n;
                ob[off] = fb[off] + acc2[mt][nt][r];
            }
}

// ---------------------------------------------------------------------------
extern "C" void kernel_launch(void* const* d_in, const int* in_sizes, int n_in,
                              void* d_out, int out_size, void* d_ws, size_t ws_size,
                              hipStream_t stream) {
    const float* f         = (const float*)d_in[0];
    const float* ln_gamma  = (const float*)d_in[1];
    const float* ln_beta   = (const float*)d_in[2];
    const float* w_expand  = (const float*)d_in[3];
    const float* freq_real = (const float*)d_in[4];
    // d_in[5] = freq_imag: provably unused (Re((r+ij)*x) for real x = r*x)
    const float* w_poly    = (const float*)d_in[6];
    const float* w_dw      = (const float*)d_in[7];
    const float* w_pw      = (const float*)d_in[8];
    const float* w_final   = (const float*)d_in[9];
    float* out = (float*)d_out;

    // workspace layout
    char* ws = (char*)d_ws;
    __hip_bfloat16* f5 = (__hip_bfloat16*)ws;                    // 64 MiB
    char* p = ws + (size_t)67108864;
    float* W1g   = (float*)p;            p += (size_t)C2 * Cc * 4;     // 512 KB
    float* bias1 = (float*)p;            p += (size_t)C2 * 4;          // 2 KB
    float* muA   = (float*)p;            p += (size_t)Pp * 4;          // 256 KB
    float* rstdA = (float*)p;            p += (size_t)Pp * 4;          // 256 KB
    __hip_bfloat16* w_pw_b    = (__hip_bfloat16*)p;  p += (size_t)C2 * C2 * 2;  // 512 KB
    __hip_bfloat16* w_final_b = (__hip_bfloat16*)p;  p += (size_t)Cc * C2 * 2;  // 256 KB

    combine_weights<<<dim3(C2), dim3(256), 0, stream>>>(
        w_expand, freq_real, w_poly, ln_gamma, ln_beta, W1g, bias1);

    to_bf16<<<dim3((C2 * C2 / 4 + 255) / 256), dim3(256), 0, stream>>>(
        w_pw, w_pw_b, C2 * C2);
    to_bf16<<<dim3((Cc * C2 / 4 + 255) / 256), dim3(256), 0, stream>>>(
        w_final, w_final_b, Cc * C2);

    ln_stats<<<dim3(Pp / 256), dim3(256), 0, stream>>>(f, muA, rstdA);

    gemm1<<<dim3(8, 64, Bn), dim3(256), 0, stream>>>(
        f, W1g, bias1, muA, rstdA, f5);

    fused_tail<<<dim3(Ww / TN3, Hh, Bn), dim3(256), 0, stream>>>(
        f5, w_dw, w_pw_b, w_final_b, f, out);
}

// Round 3
// 469.591 us; speedup vs baseline: 3.6157x; 1.4871x over previous
//
#include <hip/hip_runtime.h>
#include <hip/hip_bf16.h>
#include <math.h>

// Problem constants
#define Bn 16
#define Cc 256
#define Hh 64
#define Ww 64
#define HW 4096
#define C2 512
#define Pp 65536          // Bn*HW
#define EPSc 1e-5f

typedef __attribute__((ext_vector_type(8))) short short8;
typedef __attribute__((ext_vector_type(4))) float floatx4;

// ---------------------------------------------------------------------------
// Kernel 0: combine weights.
// W1[o,c]  = sum_m w_poly[o,m] * freq_real[m] * w_expand[m,c]
// W1g_b[o,c] = bf16(W1[o,c] * gamma[c])
// bias1[o] = sum_c W1[o,c] * beta[c]
// wsum[o]  = sum_c W1[o,c] * gamma[c]   (for LN-after-GEMM refactor)
// ---------------------------------------------------------------------------
__global__ __launch_bounds__(256)
void combine_weights(const float* __restrict__ w_expand,
                     const float* __restrict__ freq_real,
                     const float* __restrict__ w_poly,
                     const float* __restrict__ gamma,
                     const float* __restrict__ beta,
                     __hip_bfloat16* __restrict__ W1g_b,
                     float* __restrict__ bias1,
                     float* __restrict__ wsum) {
    int o = blockIdx.x;
    int c = threadIdx.x;
    float acc = 0.f;
    const float* wp = w_poly + (size_t)o * C2;
    for (int m = 0; m < C2; ++m) {
        acc += wp[m] * freq_real[m] * w_expand[(size_t)m * Cc + c];
    }
    float wg = acc * gamma[c];
    W1g_b[(size_t)o * Cc + c] = __float2bfloat16(wg);
    __shared__ float redB[256];
    __shared__ float redG[256];
    redB[c] = acc * beta[c];
    redG[c] = wg;
    __syncthreads();
    for (int s = 128; s > 0; s >>= 1) {
        if (c < s) { redB[c] += redB[c + s]; redG[c] += redG[c + s]; }
        __syncthreads();
    }
    if (c == 0) { bias1[o] = redB[0]; wsum[o] = redG[0]; }
}

// ---------------------------------------------------------------------------
// Kernel 0b: fp32 -> bf16 weight conversion (w_pw 512x512, w_final 256x512)
// ---------------------------------------------------------------------------
__global__ __launch_bounds__(256)
void to_bf16(const float* __restrict__ a, __hip_bfloat16* __restrict__ o, int n) {
    int i = (blockIdx.x * 256 + threadIdx.x) * 4;
    if (i < n) {
        float4 v = *(const float4*)&a[i];
        __hip_bfloat16 r[4];
        r[0] = __float2bfloat16(v.x);
        r[1] = __float2bfloat16(v.y);
        r[2] = __float2bfloat16(v.z);
        r[3] = __float2bfloat16(v.w);
        *(uint2*)&o[i] = *(const uint2*)r;
    }
}

// ---------------------------------------------------------------------------
// Kernel 1: fused LN + GEMM1 (MFMA).
// Uses LN linearity: f5[m,n] = r[n]*(G[m,n] - mu[n]*wsum[m]) + bias1[m],
// where G = W1g_bf16 @ raw_x_bf16. One block = 64 positions, full M=512.
// Each wave: 128 m-rows x 64 n. A-frags double-buffered from global (L2).
// ---------------------------------------------------------------------------
#define G1P 264   // LDS pitch in bf16 elems (mult of 8 -> 16B-aligned rows)

__global__ __launch_bounds__(256, 2)
void gemm1_fused(const float* __restrict__ f,
                 const __hip_bfloat16* __restrict__ W1g_b,
                 const float* __restrict__ bias1,
                 const float* __restrict__ wsum,
                 __hip_bfloat16* __restrict__ f5) {
    __shared__ __hip_bfloat16 Bs[64 * G1P];   // raw x, [n][k], 33,792 B
    __shared__ float redS[16 * 64];
    __shared__ float redQ[16 * 64];
    __shared__ float mu_s[64], rs_s[64];

    int blk = blockIdx.x;          // 0..1023
    int p0 = blk * 64;
    int b = p0 >> 12;
    int s0 = p0 & 4095;
    int tid = threadIdx.x;
    int lane = tid & 63, wave = tid >> 6;
    int col = lane & 15, quad = lane >> 4;
    int x = tid & 15, g = tid >> 4;

    const float* fb = f + (size_t)b * Cc * HW + s0 + x * 4;

    // ---- stage raw x as bf16 into Bs[n][k] + partial LN sums ----
    float lsum[4] = {0.f, 0.f, 0.f, 0.f};
    float lsq[4]  = {0.f, 0.f, 0.f, 0.f};
    unsigned* dst = (unsigned*)&Bs[0];
#pragma unroll
    for (int it = 0; it < 8; ++it) {
        int cpair = it * 16 + g;           // 0..127
        int c = cpair * 2;
        float4 v0 = *(const float4*)&fb[(size_t)c * HW];
        float4 v1 = *(const float4*)&fb[(size_t)(c + 1) * HW];
        float a0[4] = {v0.x, v0.y, v0.z, v0.w};
        float a1[4] = {v1.x, v1.y, v1.z, v1.w};
#pragma unroll
        for (int j = 0; j < 4; ++j) {
            lsum[j] += a0[j] + a1[j];
            lsq[j]  += a0[j] * a0[j] + a1[j] * a1[j];
            __hip_bfloat16 b0 = __float2bfloat16(a0[j]);
            __hip_bfloat16 b1 = __float2bfloat16(a1[j]);
            unsigned pk = ((unsigned)__bfloat16_as_ushort(b1) << 16) |
                          (unsigned)__bfloat16_as_ushort(b0);
            dst[(size_t)(x * 4 + j) * (G1P / 2) + cpair] = pk;
        }
    }
#pragma unroll
    for (int j = 0; j < 4; ++j) {
        redS[g * 64 + x * 4 + j] = lsum[j];
        redQ[g * 64 + x * 4 + j] = lsq[j];
    }

    // prefetch first A-frags while staging drains (global, no LDS dep)
    int wm0 = wave * 128;
    const __hip_bfloat16* Ab = W1g_b + (size_t)(wm0 + col) * Cc + quad * 8;
    short8 a_cur[8], a_nxt[8];
#pragma unroll
    for (int mt = 0; mt < 8; ++mt)
        a_cur[mt] = *(const short8*)(Ab + (size_t)mt * 16 * Cc);

    __syncthreads();

    // reducers (wave 0, tid<64): per-position mu / rstd
    if (tid < 64) {
        float s = 0.f, q = 0.f;
#pragma unroll
        for (int gg = 0; gg < 16; ++gg) {
            s += redS[gg * 64 + tid];
            q += redQ[gg * 64 + tid];
        }
        float m = s * (1.0f / 256.0f);
        mu_s[tid] = m;
        rs_s[tid] = rsqrtf(q * (1.0f / 256.0f) - m * m + EPSc);
    }

    // ---- MFMA: G = W1g @ x_raw, double-buffered A ----
    floatx4 acc[8][4];
#pragma unroll
    for (int mt = 0; mt < 8; ++mt)
#pragma unroll
        for (int nt = 0; nt < 4; ++nt)
            acc[mt][nt] = (floatx4){0.f, 0.f, 0.f, 0.f};

#pragma unroll
    for (int ks = 0; ks < 8; ++ks) {
        int k0 = ks * 32;
        if (ks < 7) {
#pragma unroll
            for (int mt = 0; mt < 8; ++mt)
                a_nxt[mt] = *(const short8*)(Ab + (size_t)mt * 16 * Cc + k0 + 32);
        }
        short8 bf[4];
#pragma unroll
        for (int nt = 0; nt < 4; ++nt)
            bf[nt] = *(const short8*)&Bs[(size_t)(nt * 16 + col) * G1P + k0 + quad * 8];
#pragma unroll
        for (int mt = 0; mt < 8; ++mt)
#pragma unroll
            for (int nt = 0; nt < 4; ++nt)
                acc[mt][nt] = __builtin_amdgcn_mfma_f32_16x16x32_bf16(
                    a_cur[mt], bf[nt], acc[mt][nt], 0, 0, 0);
        if (ks < 7) {
#pragma unroll
            for (int mt = 0; mt < 8; ++mt) a_cur[mt] = a_nxt[mt];
        }
    }

    __syncthreads();   // mu_s/rs_s written by wave-0 reducers before its MFMA

    // ---- epilogue: f5 = (G - mu*wsum)*rstd + bias1 ----
    __hip_bfloat16* f5b = f5 + (size_t)b * C2 * HW + s0;
#pragma unroll
    for (int mt = 0; mt < 8; ++mt) {
        float bi[4], ws4[4];
#pragma unroll
        for (int r = 0; r < 4; ++r) {
            int m = wm0 + mt * 16 + quad * 4 + r;
            bi[r] = bias1[m];
            ws4[r] = wsum[m];
        }
#pragma unroll
        for (int nt = 0; nt < 4; ++nt) {
            int n = nt * 16 + col;
            float mn = mu_s[n], rn = rs_s[n];
#pragma unroll
            for (int r = 0; r < 4; ++r) {
                int m = wm0 + mt * 16 + quad * 4 + r;
                float v = (acc[mt][nt][r] - mn * ws4[r]) * rn + bi[r];
                f5b[(size_t)m * HW + n] = __float2bfloat16(v);
            }
        }
    }
}

// ---------------------------------------------------------------------------
// Kernel 3: fused tail, MFMA + explicit A-frag double-buffer prefetch.
//  phase 0: tT[n][k] = dwconv3x3(f5) as bf16 -> LDS (32 x 520 = 33.3 KB)
//  phase 1: g = w_pw @ t via mfma; gelu(g)*g -> back into tT
//  phase 2: f8 = w_final @ f7 via mfma; out = f + f8
// ---------------------------------------------------------------------------
#define TN3 32
#define TPITCH 520

__global__ __launch_bounds__(256, 3)
void fused_tail(const __hip_bfloat16* __restrict__ f5,
                const float* __restrict__ w_dw,
                const __hip_bfloat16* __restrict__ w_pw_b,
                const __hip_bfloat16* __restrict__ w_final_b,
                const float* __restrict__ f,
                float* __restrict__ out) {
    __shared__ __hip_bfloat16 tT[TN3 * TPITCH];   // 33,280 B, reused t -> f7

    int wt = blockIdx.x;       // 0..1
    int h  = blockIdx.y;       // 0..63
    int b  = blockIdx.z;       // 0..15
    int w0 = wt * TN3;
    int tid = threadIdx.x;
    int lane = tid & 63;
    int wave = tid >> 6;
    int col = lane & 15;
    int quad = lane >> 4;

    // ---- phase 0: depthwise 3x3 -> tT[n][k] (bf16) ----
    const __hip_bfloat16* f5b = f5 + (size_t)b * C2 * HW;
#pragma unroll
    for (int it = 0; it < 8; ++it) {
        int t = it * 256 + tid;
        int k = t >> 2;
        int n0 = (t & 3) * 8;
        int w = w0 + n0;
        const float* wd = w_dw + k * 9;
        float wreg[9];
#pragma unroll
        for (int i = 0; i < 9; ++i) wreg[i] = wd[i];
        float win[3][10];
#pragma unroll
        for (int dy = 0; dy < 3; ++dy) {
            int hh = h + dy - 1;
            if ((unsigned)hh < Hh) {
                const __hip_bfloat16* row = f5b + (size_t)k * HW + hh * Ww;
                uint4 v8 = *(const uint4*)&row[w];
                const __hip_bfloat16* pv = (const __hip_bfloat16*)&v8;
#pragma unroll
                for (int j = 0; j < 8; ++j) win[dy][j + 1] = __bfloat162float(pv[j]);
                win[dy][0] = (w > 0) ? __bfloat162float(row[w - 1]) : 0.f;
                win[dy][9] = (w + 8 < Ww) ? __bfloat162float(row[w + 8]) : 0.f;
            } else {
#pragma unroll
                for (int j = 0; j < 10; ++j) win[dy][j] = 0.f;
            }
        }
#pragma unroll
        for (int j = 0; j < 8; ++j) {
            float acc = 0.f;
#pragma unroll
            for (int dy = 0; dy < 3; ++dy)
#pragma unroll
                for (int dx = 0; dx < 3; ++dx)
                    acc += wreg[dy * 3 + dx] * win[dy][j + dx];
            tT[(n0 + j) * TPITCH + k] = __float2bfloat16(acc);
        }
    }

    // ---- phase 1: g = w_pw @ t, A double-buffered from global ----
    int wm0 = wave * 128;
    const __hip_bfloat16* Ap = w_pw_b + (size_t)(wm0 + col) * C2 + quad * 8;
    short8 a_cur[8], a_nxt[8];
#pragma unroll
    for (int mt = 0; mt < 8; ++mt)
        a_cur[mt] = *(const short8*)(Ap + (size_t)mt * 16 * C2);

    __syncthreads();   // phase 0 done

    floatx4 acc[8][2];
#pragma unroll
    for (int mt = 0; mt < 8; ++mt) {
        acc[mt][0] = (floatx4){0.f, 0.f, 0.f, 0.f};
        acc[mt][1] = (floatx4){0.f, 0.f, 0.f, 0.f};
    }

#pragma unroll
    for (int ks = 0; ks < 16; ++ks) {
        int k0 = ks * 32;
        if (ks < 15) {
#pragma unroll
            for (int mt = 0; mt < 8; ++mt)
                a_nxt[mt] = *(const short8*)(Ap + (size_t)mt * 16 * C2 + k0 + 32);
        }
        short8 bf0 = *(const short8*)&tT[(size_t)col * TPITCH + k0 + quad * 8];
        short8 bf1 = *(const short8*)&tT[(size_t)(16 + col) * TPITCH + k0 + quad * 8];
#pragma unroll
        for (int mt = 0; mt < 8; ++mt) {
            acc[mt][0] = __builtin_amdgcn_mfma_f32_16x16x32_bf16(a_cur[mt], bf0, acc[mt][0], 0, 0, 0);
            acc[mt][1] = __builtin_amdgcn_mfma_f32_16x16x32_bf16(a_cur[mt], bf1, acc[mt][1], 0, 0, 0);
        }
        if (ks < 15) {
#pragma unroll
            for (int mt = 0; mt < 8; ++mt) a_cur[mt] = a_nxt[mt];
        }
    }
    __syncthreads();   // everyone done reading tT

    // ---- gating: f7 = gelu(g)*g -> back into tT (same [n][k] layout) ----
#pragma unroll
    for (int mt = 0; mt < 8; ++mt)
#pragma unroll
        for (int nt = 0; nt < 2; ++nt) {
            __hip_bfloat16 v4[4];
#pragma unroll
            for (int r = 0; r < 4; ++r) {
                float v = acc[mt][nt][r];
                float gl = 0.5f * v * (1.0f + erff(v * 0.70710678118f));
                v4[r] = __float2bfloat16(gl * v);
            }
            *(uint2*)&tT[(size_t)(nt * 16 + col) * TPITCH + wm0 + mt * 16 + quad * 4] = *(const uint2*)v4;
        }

    // ---- phase 2: f8 = w_final @ f7, A double-buffered ----
    int wm2 = wave * 64;
    const __hip_bfloat16* Af = w_final_b + (size_t)(wm2 + col) * C2 + quad * 8;
    short8 c_cur[4], c_nxt[4];
#pragma unroll
    for (int mt = 0; mt < 4; ++mt)
        c_cur[mt] = *(const short8*)(Af + (size_t)mt * 16 * C2);

    __syncthreads();   // f7 fully written

    floatx4 acc2[4][2];
#pragma unroll
    for (int mt = 0; mt < 4; ++mt) {
        acc2[mt][0] = (floatx4){0.f, 0.f, 0.f, 0.f};
        acc2[mt][1] = (floatx4){0.f, 0.f, 0.f, 0.f};
    }

#pragma unroll
    for (int ks = 0; ks < 16; ++ks) {
        int k0 = ks * 32;
        if (ks < 15) {
#pragma unroll
            for (int mt = 0; mt < 4; ++mt)
                c_nxt[mt] = *(const short8*)(Af + (size_t)mt * 16 * C2 + k0 + 32);
        }
        short8 bf0 = *(const short8*)&tT[(size_t)col * TPITCH + k0 + quad * 8];
        short8 bf1 = *(const short8*)&tT[(size_t)(16 + col) * TPITCH + k0 + quad * 8];
#pragma unroll
        for (int mt = 0; mt < 4; ++mt) {
            acc2[mt][0] = __builtin_amdgcn_mfma_f32_16x16x32_bf16(c_cur[mt], bf0, acc2[mt][0], 0, 0, 0);
            acc2[mt][1] = __builtin_amdgcn_mfma_f32_16x16x32_bf16(c_cur[mt], bf1, acc2[mt][1], 0, 0, 0);
        }
        if (ks < 15) {
#pragma unroll
            for (int mt = 0; mt < 4; ++mt) c_cur[mt] = c_nxt[mt];
        }
    }

    // ---- epilogue: out = f + f8 ----
    const float* fb = f + (size_t)b * Cc * HW + h * Ww + w0;
    float* ob = out + (size_t)b * Cc * HW + h * Ww + w0;
#pragma unroll
    for (int mt = 0; mt < 4; ++mt)
#pragma unroll
        for (int nt = 0; nt < 2; ++nt)
#pragma unroll
            for (int r = 0; r < 4; ++r) {
                int m = wm2 + mt * 16 + quad * 4 + r;
                int n = nt * 16 + col;
                size_t off = (size_t)m * HW + n;
                ob[off] = fb[off] + acc2[mt][nt][r];
            }
}

// ---------------------------------------------------------------------------
extern "C" void kernel_launch(void* const* d_in, const int* in_sizes, int n_in,
                              void* d_out, int out_size, void* d_ws, size_t ws_size,
                              hipStream_t stream) {
    const float* f         = (const float*)d_in[0];
    const float* ln_gamma  = (const float*)d_in[1];
    const float* ln_beta   = (const float*)d_in[2];
    const float* w_expand  = (const float*)d_in[3];
    const float* freq_real = (const float*)d_in[4];
    // d_in[5] = freq_imag: provably unused (Re((r+ij)*x) for real x = r*x)
    const float* w_poly    = (const float*)d_in[6];
    const float* w_dw      = (const float*)d_in[7];
    const float* w_pw      = (const float*)d_in[8];
    const float* w_final   = (const float*)d_in[9];
    float* out = (float*)d_out;

    // workspace layout
    char* ws = (char*)d_ws;
    __hip_bfloat16* f5 = (__hip_bfloat16*)ws;                       // 64 MiB
    char* p = ws + (size_t)67108864;
    __hip_bfloat16* W1g_b = (__hip_bfloat16*)p;  p += (size_t)C2 * Cc * 2;   // 256 KB
    float* bias1 = (float*)p;                    p += (size_t)C2 * 4;
    float* wsum  = (float*)p;                    p += (size_t)C2 * 4;
    __hip_bfloat16* w_pw_b    = (__hip_bfloat16*)p;  p += (size_t)C2 * C2 * 2;
    __hip_bfloat16* w_final_b = (__hip_bfloat16*)p;  p += (size_t)Cc * C2 * 2;

    combine_weights<<<dim3(C2), dim3(256), 0, stream>>>(
        w_expand, freq_real, w_poly, ln_gamma, ln_beta, W1g_b, bias1, wsum);

    to_bf16<<<dim3((C2 * C2 / 4 + 255) / 256), dim3(256), 0, stream>>>(
        w_pw, w_pw_b, C2 * C2);
    to_bf16<<<dim3((Cc * C2 / 4 + 255) / 256), dim3(256), 0, stream>>>(
        w_final, w_final_b, Cc * C2);

    gemm1_fused<<<dim3(Pp / 64), dim3(256), 0, stream>>>(
        f, W1g_b, bias1, wsum, f5);

    fused_tail<<<dim3(Ww / TN3, Hh, Bn), dim3(256), 0, stream>>>(
        f5, w_dw, w_pw_b, w_final_b, f, out);
}